// Round 13
// baseline (205.281 us; speedup 1.0000x reference)
//
#include <hip/hip_runtime.h>
#include <math.h>

#define NN 50000
#define EE 800000
#define DDIM 128
#define NROWS 100000   // B*N
#define NB 49          // ceil(NN/1024) scan blocks

typedef __attribute__((ext_vector_type(8))) short bf16x8;
typedef __attribute__((ext_vector_type(4))) float f32x4;

__device__ __forceinline__ float lrelu(float x) { return x > 0.f ? x : 0.2f * x; }
// fast ELU: hardware v_exp_f32; for x<=0, expf(x)-1 (abs err ~1e-7 — far
// under the 0.049 threshold). Avoids expm1f's ~25-instruction expansion.
__device__ __forceinline__ float eluf(float x)  {
    float e = __expf(x);
    return x > 0.f ? x : e - 1.f;
}

__device__ __forceinline__ unsigned short f2bf(float f) {
    unsigned int u = __float_as_uint(f);
    u += 0x7fffu + ((u >> 16) & 1u);          // RNE
    return (unsigned short)(u >> 16);
}
__device__ __forceinline__ float bflo(unsigned int v) { return __uint_as_float(v << 16); }
__device__ __forceinline__ float bfhi(unsigned int v) { return __uint_as_float(v & 0xffff0000u); }

// ---------------------------------------------------------------------------
// MFMA GEMM: Wh16[row][o] = bf16( sum_k h[row][k] * Wfc[o][k] )
// + fused scores written as [node][batch] float pairs.
// Epilogue: acc -> LDS (272B-stride rows) -> coalesced dwordx4 stores.
// ---------------------------------------------------------------------------
__global__ __launch_bounds__(256) void gemm_kernel(const float* __restrict__ h,
                                                   const float* __restrict__ Wfc,
                                                   const float* __restrict__ Wat,
                                                   unsigned short* __restrict__ Wh16,
                                                   float* __restrict__ ssrc2,
                                                   float* __restrict__ sdst2) {
    __shared__ uint4 Wlds4[2048];              // 32 KB: 128 cols x 256 B
    __shared__ unsigned short stage[64 * 136]; // 17408 B: 64 rows x 272 B
    char* WldsB  = (char*)Wlds4;
    char* stageB = (char*)stage;
    const int tid = threadIdx.x;

    // ---- stage W -> LDS bf16, swizzled ----
    {
        const int colw = tid & 127;
        const int kh   = tid >> 7;             // 0..1
#pragma unroll
        for (int q = 0; q < 8; ++q) {
            int k0 = kh * 64 + q * 8;
            float4 w0 = *(const float4*)&Wfc[colw * DDIM + k0];
            float4 w1 = *(const float4*)&Wfc[colw * DDIM + k0 + 4];
            union { uint4 q4; unsigned short u[8]; } pk;
            pk.u[0] = f2bf(w0.x); pk.u[1] = f2bf(w0.y);
            pk.u[2] = f2bf(w0.z); pk.u[3] = f2bf(w0.w);
            pk.u[4] = f2bf(w1.x); pk.u[5] = f2bf(w1.y);
            pk.u[6] = f2bf(w1.z); pk.u[7] = f2bf(w1.w);
            int ba = colw * 256 + k0 * 2;
            ba ^= (colw & 15) << 4;
            *(uint4*)(WldsB + ba) = pk.q4;
        }
    }
    __syncthreads();

    const int lane = tid & 63;
    const int wv   = tid >> 6;
    const long mbase = (long)blockIdx.x * 64 + wv * 16;
    if (mbase >= NROWS) return;                // tail block: extra waves idle

    const int c  = lane & 15;                  // A row / D col within tile
    const int kg = lane >> 4;                  // k-group 0..3

    // ---- A fragments: global fp32 -> bf16 regs ----
    union Af { bf16x8 v; unsigned short u[8]; };
    Af af[4];
    const float* arow = h + (mbase + c) * DDIM + kg * 8;
#pragma unroll
    for (int kk = 0; kk < 4; ++kk) {
        float4 x = *(const float4*)(arow + kk * 32);
        float4 y = *(const float4*)(arow + kk * 32 + 4);
        af[kk].u[0] = f2bf(x.x); af[kk].u[1] = f2bf(x.y);
        af[kk].u[2] = f2bf(x.z); af[kk].u[3] = f2bf(x.w);
        af[kk].u[4] = f2bf(y.x); af[kk].u[5] = f2bf(y.y);
        af[kk].u[6] = f2bf(y.z); af[kk].u[7] = f2bf(y.w);
    }

    // ---- MFMA main: 8 col-tiles x 4 k-steps ----
    f32x4 acc[8];
#pragma unroll
    for (int t = 0; t < 8; ++t) acc[t] = (f32x4){0.f, 0.f, 0.f, 0.f};
#pragma unroll
    for (int t = 0; t < 8; ++t) {
        int colbase = (t * 16 + c) * 256;
        int sw = c << 4;
#pragma unroll
        for (int kk = 0; kk < 4; ++kk) {
            int ba = (colbase + kk * 64 + kg * 16) ^ sw;
            bf16x8 b = *(const bf16x8*)(WldsB + ba);
            acc[t] = __builtin_amdgcn_mfma_f32_16x16x32_bf16(af[kk].v, b, acc[t], 0, 0, 0);
        }
    }

    // ---- acc -> LDS stage (D: col = t*16+c, local row = wv*16 + kg*4 + r) ----
#pragma unroll
    for (int t = 0; t < 8; ++t) {
#pragma unroll
        for (int r = 0; r < 4; ++r) {
            int lrow = wv * 16 + kg * 4 + r;
            *(unsigned short*)(stageB + lrow * 272 + (t * 16 + c) * 2) = f2bf(acc[t][r]);
        }
    }
    // wave-local readout: wave's 16 rows = contiguous 4KB in global
    {
        const long gbase = mbase * 256;        // byte offset into Wh16
        const int  lbase = wv * 16 * 272;
#pragma unroll
        for (int q = 0; q < 4; ++q) {
            int f = q * 1024 + lane * 16;      // flat byte idx in wave's 4KB
            uint4 v = *(const uint4*)(stageB + lbase + (f >> 8) * 272 + (f & 255));
            *(uint4*)((char*)Wh16 + gbase + f) = v;
        }
    }

    // ---- fused scores ----
    float asv[8], adv[8];
#pragma unroll
    for (int t = 0; t < 8; ++t) {
        asv[t] = Wat[t * 16 + c];
        adv[t] = Wat[DDIM + t * 16 + c];
    }
#pragma unroll
    for (int r = 0; r < 4; ++r) {
        float ps = 0.f, pd = 0.f;
#pragma unroll
        for (int t = 0; t < 8; ++t) {
            ps += acc[t][r] * asv[t];
            pd += acc[t][r] * adv[t];
        }
#pragma unroll
        for (int o = 1; o <= 8; o <<= 1) {
            ps += __shfl_xor(ps, o);
            pd += __shfl_xor(pd, o);
        }
        if (c == 0) {
            long row = mbase + kg * 4 + r;       // row = b*NN + n
            int b = row >= NN;
            long n = row - (long)b * NN;
            ssrc2[2 * n + b] = ps;
            sdst2[2 * n + b] = pd;
        }
    }
}

// ---------------------------------------------------------------------------
// CSR build: degree -> 3-kernel parallel exclusive scan -> scatter
// ---------------------------------------------------------------------------
__global__ __launch_bounds__(256) void degree_kernel(const int* __restrict__ ei,
                                                     int* __restrict__ deg) {
    int e = blockIdx.x * 256 + threadIdx.x;
    if (e < EE) atomicAdd(&deg[ei[EE + e]], 1);
}

__global__ __launch_bounds__(1024) void scan1_kernel(const int* __restrict__ deg,
                                                     int* __restrict__ offs,
                                                     int* __restrict__ bsum) {
    __shared__ int wsum[16];
    const int tid = threadIdx.x, lane = tid & 63, wid = tid >> 6;
    const int i = blockIdx.x * 1024 + tid;
    int v = (i < NN) ? deg[i] : 0;
    int x = v;
#pragma unroll
    for (int o = 1; o < 64; o <<= 1) {
        int t = __shfl_up(x, o);
        if (lane >= o) x += t;
    }
    if (lane == 63) wsum[wid] = x;
    __syncthreads();
    if (wid == 0) {
        int s = (lane < 16) ? wsum[lane] : 0;
#pragma unroll
        for (int o = 1; o < 16; o <<= 1) {
            int t = __shfl_up(s, o);
            if (lane >= o) s += t;
        }
        if (lane < 16) wsum[lane] = s;
    }
    __syncthreads();
    int waveoff = (wid > 0) ? wsum[wid - 1] : 0;
    if (i < NN) offs[i] = x - v + waveoff;          // block-local exclusive
    if (tid == 0) bsum[blockIdx.x] = wsum[15];      // block total
}

__global__ __launch_bounds__(64) void scan2_kernel(const int* __restrict__ bsum,
                                                   int* __restrict__ bscan,
                                                   int* __restrict__ offs) {
    const int lane = threadIdx.x;
    int v = (lane < NB) ? bsum[lane] : 0;
    int x = v;
#pragma unroll
    for (int o = 1; o < 64; o <<= 1) {
        int t = __shfl_up(x, o);
        if (lane >= o) x += t;
    }
    if (lane < NB) bscan[lane] = x - v;
    if (lane == 63) offs[NN] = x;                   // total = EE
}

__global__ __launch_bounds__(1024) void scan3_kernel(int* __restrict__ offs,
                                                     const int* __restrict__ bscan) {
    const int i = blockIdx.x * 1024 + threadIdx.x;
    if (i < NN) offs[i] += bscan[blockIdx.x];
}

// scatter: per-batch 8B records {src, wbits} in CSR order
__global__ __launch_bounds__(256) void scatter_kernel(const int* __restrict__ ei,
                                                      const int* __restrict__ offs,
                                                      int* __restrict__ cnt2,
                                                      const float* __restrict__ ssrc2,
                                                      const float* __restrict__ sdst2,
                                                      uint2* __restrict__ rec0,
                                                      uint2* __restrict__ rec1) {
    int e = blockIdx.x * 256 + threadIdx.x;
    if (e < EE) {
        int dst = ei[EE + e];
        int src = ei[e];
        int p = offs[dst] + atomicAdd(&cnt2[dst], 1);
        float2 ss = ((const float2*)ssrc2)[src];
        float2 sd = ((const float2*)sdst2)[dst];
        float e0 = __expf(lrelu(ss.x + sd.x));
        float e1 = __expf(lrelu(ss.y + sd.y));
        rec0[p] = make_uint2((unsigned)src, __float_as_uint(e0));
        rec1[p] = make_uint2((unsigned)src, __float_as_uint(e1));
    }
}

// ---------------------------------------------------------------------------
// aggregate: one wave per (dst, batch, feature-half). Quadrant (b,half) is
// steered to a fixed XCD pair via bid%8 round-robin so each XCD's gather
// working set is one 6.4 MB quadrant (fits ~L2). 8 lanes per edge load
// uint4 = 128B half-row; 8 edges in flight per load instruction; edge
// records read via group-broadcast loads (no shfl machinery).
// ---------------------------------------------------------------------------
__global__ __launch_bounds__(256) void aggregate_kernel(const char* __restrict__ WhB,
                                                        const int* __restrict__ offs,
                                                        const uint2* __restrict__ rec0,
                                                        const uint2* __restrict__ rec1,
                                                        float* __restrict__ out) {
    const int tid  = threadIdx.x;
    const int lane = tid & 63;
    const int wid  = tid >> 6;
    const int bid  = blockIdx.x;

    const int xcd  = bid & 7;
    const int quad = xcd >> 1;                 // 0..3
    const int b    = quad >> 1;                // batch
    const int half = quad & 1;                 // feature half
    const int widx = ((bid >> 3) << 1) + (xcd & 1);   // [0,12500)
    const int d    = widx * 4 + wid;                  // [0,50000)

    const int grp = lane >> 3;                 // 0..7: edge slot
    const int fl  = lane & 7;                  // 0..7: 16B feature slice

    float* o = out + ((long)b * NN + d) * DDIM + half * 64;

    const int base   = offs[d];
    const int degree = offs[d + 1] - base;
    if (degree == 0) {
        if (lane < 8) {
            f32x4 z = {0.f, 0.f, 0.f, 0.f};
            __builtin_nontemporal_store(z, (f32x4*)o + 2 * fl);
            __builtin_nontemporal_store(z, (f32x4*)o + 2 * fl + 1);
        }
        return;
    }

    const uint2* recs = (b ? rec1 : rec0) + base;
    const char* WT = WhB + (long)b * NN * 256 + half * 128 + fl * 16;

    f32x4 accA = {0,0,0,0}, accB = {0,0,0,0};
    float ds = 0.f;

    for (int e = grp; e < degree; e += 8) {
        uint2 r = recs[e];                     // broadcast within 8-lane group
        float w = __uint_as_float(r.y);
        ds += w;
        uint4 v = *(const uint4*)(WT + (long)r.x * 256);
        accA.x += w * bflo(v.x); accA.y += w * bfhi(v.x);
        accA.z += w * bflo(v.y); accA.w += w * bfhi(v.y);
        accB.x += w * bflo(v.z); accB.y += w * bfhi(v.z);
        accB.z += w * bflo(v.w); accB.w += w * bfhi(v.w);
    }

    // merge the 8 edge-groups (same feature slice at lanes l^8k)
#pragma unroll
    for (int m = 32; m >= 8; m >>= 1) {
        accA.x += __shfl_xor(accA.x, m); accA.y += __shfl_xor(accA.y, m);
        accA.z += __shfl_xor(accA.z, m); accA.w += __shfl_xor(accA.w, m);
        accB.x += __shfl_xor(accB.x, m); accB.y += __shfl_xor(accB.y, m);
        accB.z += __shfl_xor(accB.z, m); accB.w += __shfl_xor(accB.w, m);
        ds     += __shfl_xor(ds, m);
    }
    const float inv = 1.f / ds;

    if (lane < 8) {
        f32x4 rA = { eluf(accA.x * inv), eluf(accA.y * inv),
                     eluf(accA.z * inv), eluf(accA.w * inv) };
        f32x4 rB = { eluf(accB.x * inv), eluf(accB.y * inv),
                     eluf(accB.z * inv), eluf(accB.w * inv) };
        __builtin_nontemporal_store(rA, (f32x4*)o + 2 * fl);
        __builtin_nontemporal_store(rB, (f32x4*)o + 2 * fl + 1);
    }
}

// ---------------------------------------------------------------------------
extern "C" void kernel_launch(void* const* d_in, const int* in_sizes, int n_in,
                              void* d_out, int out_size, void* d_ws, size_t ws_size,
                              hipStream_t stream) {
    (void)in_sizes; (void)n_in; (void)out_size; (void)ws_size;
    const float* h   = (const float*)d_in[0];
    const int*   ei  = (const int*)d_in[1];
    const float* Wfc = (const float*)d_in[2];
    const float* Wat = (const float*)d_in[3];
    float* out = (float*)d_out;

    char* ws = (char*)d_ws;
    unsigned short* Wh16 = (unsigned short*)(ws + 0);   // 25,600,000 B
    float*  ssrc2 = (float*)(ws + 25600000);            //    400,000 B  [node][batch]
    float*  sdst2 = (float*)(ws + 26000000);            //    400,000 B
    uint2*  rec0  = (uint2*)(ws + 26400000);            //  6,400,000 B
    uint2*  rec1  = (uint2*)(ws + 32800000);            //  6,400,000 B
    int*    offs  = (int*)  (ws + 39200000);            //    200,448 B
    int*    deg   = (int*)  (ws + 39400448);            //    200,000 B
    int*    cnt2  = (int*)  (ws + 39600448);            //    200,000 B (contiguous w/ deg)
    int*    bsum  = (int*)  (ws + 39800448);            //        256 B
    int*    bscan = (int*)  (ws + 39800704);            //        256 B

    hipMemsetAsync(deg, 0, 400000, stream);   // zero deg + cnt2

    gemm_kernel<<<(NROWS + 63) / 64, 256, 0, stream>>>(h, Wfc, Wat, Wh16, ssrc2, sdst2);
    degree_kernel<<<EE / 256, 256, 0, stream>>>(ei, deg);
    scan1_kernel<<<NB, 1024, 0, stream>>>(deg, offs, bsum);
    scan2_kernel<<<1, 64, 0, stream>>>(bsum, bscan, offs);
    scan3_kernel<<<NB, 1024, 0, stream>>>(offs, bscan);
    scatter_kernel<<<EE / 256, 256, 0, stream>>>(ei, offs, cnt2, ssrc2, sdst2, rec0, rec1);
    aggregate_kernel<<<50000, 256, 0, stream>>>((const char*)Wh16, offs, rec0, rec1, out);
}

// Round 16
// 178.361 us; speedup vs baseline: 1.1509x; 1.1509x over previous
//
#include <hip/hip_runtime.h>
#include <math.h>

#define NN 50000
#define EE 800000
#define DDIM 128
#define NROWS 100000   // B*N
#define NB 49          // ceil(NN/1024) scan blocks

typedef __attribute__((ext_vector_type(8))) short bf16x8;
typedef __attribute__((ext_vector_type(4))) float f32x4;

__device__ __forceinline__ float lrelu(float x) { return x > 0.f ? x : 0.2f * x; }
// fast ELU via hardware v_exp_f32 (abs err ~1e-7, validated r13)
__device__ __forceinline__ float eluf(float x)  {
    float e = __expf(x);
    return x > 0.f ? x : e - 1.f;
}

__device__ __forceinline__ unsigned short f2bf(float f) {
    unsigned int u = __float_as_uint(f);
    u += 0x7fffu + ((u >> 16) & 1u);          // RNE
    return (unsigned short)(u >> 16);
}
__device__ __forceinline__ float bflo(unsigned int v) { return __uint_as_float(v << 16); }
__device__ __forceinline__ float bfhi(unsigned int v) { return __uint_as_float(v & 0xffff0000u); }

// ---------------------------------------------------------------------------
// wprep: W fp32 -> bf16, PRE-SWIZZLED in global so gemm can stage it to LDS
// linearly via global_load_lds. LDS layout target: 16B chunk of col c,
// k-chunk q lives at byte c*256 + ((q ^ (c&15)) << 4).
// ---------------------------------------------------------------------------
__global__ __launch_bounds__(256) void wprep_kernel(const float* __restrict__ Wfc,
                                                    unsigned short* __restrict__ Wsw) {
    const int tid = threadIdx.x;
    const int col = tid & 127;
    const int kh  = tid >> 7;                  // 0..1
#pragma unroll
    for (int q8 = 0; q8 < 8; ++q8) {
        int k0 = kh * 64 + q8 * 8;
        float4 w0 = *(const float4*)&Wfc[col * DDIM + k0];
        float4 w1 = *(const float4*)&Wfc[col * DDIM + k0 + 4];
        union { uint4 q4; unsigned short u[8]; } pk;
        pk.u[0] = f2bf(w0.x); pk.u[1] = f2bf(w0.y);
        pk.u[2] = f2bf(w0.z); pk.u[3] = f2bf(w0.w);
        pk.u[4] = f2bf(w1.x); pk.u[5] = f2bf(w1.y);
        pk.u[6] = f2bf(w1.z); pk.u[7] = f2bf(w1.w);
        int chunk = (k0 >> 3) ^ (col & 15);
        *(uint4*)((char*)Wsw + col * 256 + chunk * 16) = pk.q4;
    }
}

// ---------------------------------------------------------------------------
// MFMA GEMM: Wh16[row][o] = bf16( sum_k h[row][k] * Wfc[o][k] )
// W staged to LDS via global_load_lds (pre-swizzled source, linear copy).
// Tail guard: NROWS%16==0 -> each wave's 16 rows all-valid or all-invalid;
// inactive waves still stage W + hit the barrier, with clamped A-loads.
// ---------------------------------------------------------------------------
__global__ __launch_bounds__(256) void gemm_kernel(const float* __restrict__ h,
                                                   const unsigned short* __restrict__ Wsw,
                                                   const float* __restrict__ Wat,
                                                   unsigned short* __restrict__ Wh16,
                                                   float* __restrict__ ssrc2,
                                                   float* __restrict__ sdst2) {
    __shared__ unsigned int Wlds_u32[8192];    // 32 KB: 128 cols x 256 B
    __shared__ unsigned short stage[64 * 136]; // 17408 B: 64 rows x 272 B
    char* WldsB  = (char*)Wlds_u32;
    char* stageB = (char*)stage;
    const int tid  = threadIdx.x;
    const int lane = tid & 63;
    const int wv   = tid >> 6;

    // ---- stage W -> LDS: 8 x 1KB async copies per wave (linear) ----
    {
        const char* gsrc = (const char*)Wsw + wv * 8192 + lane * 16;
        unsigned int* ldst = &Wlds_u32[wv * 2048];   // byte base wv*8192
#pragma unroll
        for (int c8 = 0; c8 < 8; ++c8) {
            __builtin_amdgcn_global_load_lds((const unsigned int*)(gsrc + c8 * 1024),
                                             ldst + c8 * 256, 16, 0, 0);
        }
    }

    const long mbase  = (long)blockIdx.x * 64 + wv * 16;
    const bool active = (mbase < NROWS);
    const long mload  = active ? mbase : 0;    // clamp OOB reads for tail waves
    const int c  = lane & 15;                  // A row / D col within tile
    const int kg = lane >> 4;                  // k-group 0..3

    // ---- A fragments: global fp32 -> bf16 regs (overlaps W staging) ----
    union Af { bf16x8 v; unsigned short u[8]; };
    Af af[4];
    const float* arow = h + (mload + c) * DDIM + kg * 8;
#pragma unroll
    for (int kk = 0; kk < 4; ++kk) {
        float4 x = *(const float4*)(arow + kk * 32);
        float4 y = *(const float4*)(arow + kk * 32 + 4);
        af[kk].u[0] = f2bf(x.x); af[kk].u[1] = f2bf(x.y);
        af[kk].u[2] = f2bf(x.z); af[kk].u[3] = f2bf(x.w);
        af[kk].u[4] = f2bf(y.x); af[kk].u[5] = f2bf(y.y);
        af[kk].u[6] = f2bf(y.z); af[kk].u[7] = f2bf(y.w);
    }
    __syncthreads();                           // drains global_load_lds
    if (!active) return;                       // tail waves: no compute/stores

    // ---- MFMA main: 8 col-tiles x 4 k-steps ----
    f32x4 acc[8];
#pragma unroll
    for (int t = 0; t < 8; ++t) acc[t] = (f32x4){0.f, 0.f, 0.f, 0.f};
#pragma unroll
    for (int t = 0; t < 8; ++t) {
        int colbase = (t * 16 + c) * 256;
        int sw = c << 4;
#pragma unroll
        for (int kk = 0; kk < 4; ++kk) {
            int ba = (colbase + kk * 64 + kg * 16) ^ sw;
            bf16x8 b = *(const bf16x8*)(WldsB + ba);
            acc[t] = __builtin_amdgcn_mfma_f32_16x16x32_bf16(af[kk].v, b, acc[t], 0, 0, 0);
        }
    }

    // ---- acc -> LDS stage (D: col = t*16+c, local row = wv*16 + kg*4 + r) ----
#pragma unroll
    for (int t = 0; t < 8; ++t) {
#pragma unroll
        for (int r = 0; r < 4; ++r) {
            int lrow = wv * 16 + kg * 4 + r;
            *(unsigned short*)(stageB + lrow * 272 + (t * 16 + c) * 2) = f2bf(acc[t][r]);
        }
    }
    // wave-local readout: wave's 16 rows = contiguous 4KB in global
    {
        const long gbase = mbase * 256;        // byte offset into Wh16
        const int  lbase = wv * 16 * 272;
#pragma unroll
        for (int q = 0; q < 4; ++q) {
            int f = q * 1024 + lane * 16;      // flat byte idx in wave's 4KB
            uint4 v = *(const uint4*)(stageB + lbase + (f >> 8) * 272 + (f & 255));
            *(uint4*)((char*)Wh16 + gbase + f) = v;
        }
    }

    // ---- fused scores ----
    float asv[8], adv[8];
#pragma unroll
    for (int t = 0; t < 8; ++t) {
        asv[t] = Wat[t * 16 + c];
        adv[t] = Wat[DDIM + t * 16 + c];
    }
#pragma unroll
    for (int r = 0; r < 4; ++r) {
        float ps = 0.f, pd = 0.f;
#pragma unroll
        for (int t = 0; t < 8; ++t) {
            ps += acc[t][r] * asv[t];
            pd += acc[t][r] * adv[t];
        }
#pragma unroll
        for (int o = 1; o <= 8; o <<= 1) {
            ps += __shfl_xor(ps, o);
            pd += __shfl_xor(pd, o);
        }
        if (c == 0) {
            long row = mbase + kg * 4 + r;       // row = b*NN + n
            int b = row >= NN;
            long n = row - (long)b * NN;
            ssrc2[2 * n + b] = ps;
            sdst2[2 * n + b] = pd;
        }
    }
}

// ---------------------------------------------------------------------------
// CSR build: degree -> 3-kernel parallel exclusive scan -> scatter
// ---------------------------------------------------------------------------
__global__ __launch_bounds__(256) void degree_kernel(const int* __restrict__ ei,
                                                     int* __restrict__ deg) {
    int e = blockIdx.x * 256 + threadIdx.x;
    if (e < EE) atomicAdd(&deg[ei[EE + e]], 1);
}

__global__ __launch_bounds__(1024) void scan1_kernel(const int* __restrict__ deg,
                                                     int* __restrict__ offs,
                                                     int* __restrict__ bsum) {
    __shared__ int wsum[16];
    const int tid = threadIdx.x, lane = tid & 63, wid = tid >> 6;
    const int i = blockIdx.x * 1024 + tid;
    int v = (i < NN) ? deg[i] : 0;
    int x = v;
#pragma unroll
    for (int o = 1; o < 64; o <<= 1) {
        int t = __shfl_up(x, o);
        if (lane >= o) x += t;
    }
    if (lane == 63) wsum[wid] = x;
    __syncthreads();
    if (wid == 0) {
        int s = (lane < 16) ? wsum[lane] : 0;
#pragma unroll
        for (int o = 1; o < 16; o <<= 1) {
            int t = __shfl_up(s, o);
            if (lane >= o) s += t;
        }
        if (lane < 16) wsum[lane] = s;
    }
    __syncthreads();
    int waveoff = (wid > 0) ? wsum[wid - 1] : 0;
    if (i < NN) offs[i] = x - v + waveoff;          // block-local exclusive
    if (tid == 0) bsum[blockIdx.x] = wsum[15];      // block total
}

__global__ __launch_bounds__(64) void scan2_kernel(const int* __restrict__ bsum,
                                                   int* __restrict__ bscan,
                                                   int* __restrict__ offs) {
    const int lane = threadIdx.x;
    int v = (lane < NB) ? bsum[lane] : 0;
    int x = v;
#pragma unroll
    for (int o = 1; o < 64; o <<= 1) {
        int t = __shfl_up(x, o);
        if (lane >= o) x += t;
    }
    if (lane < NB) bscan[lane] = x - v;
    if (lane == 63) offs[NN] = x;                   // total = EE
}

__global__ __launch_bounds__(1024) void scan3_kernel(int* __restrict__ offs,
                                                     const int* __restrict__ bscan) {
    const int i = blockIdx.x * 1024 + threadIdx.x;
    if (i < NN) offs[i] += bscan[blockIdx.x];
}

// scatter: per-batch 8B records {src, wbits} in CSR order
__global__ __launch_bounds__(256) void scatter_kernel(const int* __restrict__ ei,
                                                      const int* __restrict__ offs,
                                                      int* __restrict__ cnt2,
                                                      const float* __restrict__ ssrc2,
                                                      const float* __restrict__ sdst2,
                                                      uint2* __restrict__ rec0,
                                                      uint2* __restrict__ rec1) {
    int e = blockIdx.x * 256 + threadIdx.x;
    if (e < EE) {
        int dst = ei[EE + e];
        int src = ei[e];
        int p = offs[dst] + atomicAdd(&cnt2[dst], 1);
        float2 ss = ((const float2*)ssrc2)[src];
        float2 sd = ((const float2*)sdst2)[dst];
        float e0 = __expf(lrelu(ss.x + sd.x));
        float e1 = __expf(lrelu(ss.y + sd.y));
        rec0[p] = make_uint2((unsigned)src, __float_as_uint(e0));
        rec1[p] = make_uint2((unsigned)src, __float_as_uint(e1));
    }
}

// ---------------------------------------------------------------------------
// aggregate (r11 proven structure): one wave per (dst, batch); b = bid&1 so
// each XCD serves one batch (12.8MB footprint). 16 lanes/edge x uint4 =
// full 256B row; 4 edges per load instruction; per-batch 8B records.
// ---------------------------------------------------------------------------
__global__ __launch_bounds__(256) void aggregate_kernel(const unsigned int* __restrict__ Wh16u,
                                                        const int* __restrict__ offs,
                                                        const uint2* __restrict__ rec0,
                                                        const uint2* __restrict__ rec1,
                                                        float* __restrict__ out) {
    const int lane = threadIdx.x & 63;
    const int wid  = threadIdx.x >> 6;
    const int bid  = blockIdx.x;
    const int b    = bid & 1;
    const int d    = (bid >> 1) * 4 + wid;

    const int grp = lane >> 4;     // 0..3: which edge of the quad
    const int fl  = lane & 15;     // feature slice (8 feats = 16B)

    float* o = out + ((long)b * NN + d) * DDIM;

    const int base   = offs[d];
    const int degree = offs[d + 1] - base;
    if (degree == 0) {
        if (lane < 16) {
            float4 z = {0.f, 0.f, 0.f, 0.f};
            ((float4*)o)[2 * fl]     = z;
            ((float4*)o)[2 * fl + 1] = z;
        }
        return;
    }

    const uint2* recs = (b ? rec1 : rec0) + base;
    const unsigned int* WB = Wh16u + (long)b * NN * 64;

    f32x4 accA = {0,0,0,0}, accB = {0,0,0,0};
    float ds = 0.f;

    for (int ch = 0; ch < degree; ch += 64) {
        int i = ch + lane;
        int s = 0; float w = 0.f;
        if (i < degree) {
            uint2 r = recs[i];
            s = (int)r.x;
            w = __uint_as_float(r.y);
            ds += w;
        }
        int cnt   = min(64, degree - ch);
        int quads = (cnt + 3) >> 2;
        for (int j = 0; j < quads; ++j) {
            int idx = 4 * j + grp;               // tail lanes carry w=0
            int   sj = __shfl(s, idx);
            float wj = __shfl(w, idx);
            uint4 v = ((const uint4*)(WB + (long)sj * 64))[fl];
            accA.x += wj * bflo(v.x); accA.y += wj * bfhi(v.x);
            accA.z += wj * bflo(v.y); accA.w += wj * bfhi(v.y);
            accB.x += wj * bflo(v.z); accB.y += wj * bfhi(v.z);
            accB.z += wj * bflo(v.w); accB.w += wj * bfhi(v.w);
        }
    }

    // merge the 4 edge-groups (same feature slice at lanes l, l^16, l^32, l^48)
#pragma unroll
    for (int m = 32; m >= 16; m >>= 1) {
        accA.x += __shfl_xor(accA.x, m); accA.y += __shfl_xor(accA.y, m);
        accA.z += __shfl_xor(accA.z, m); accA.w += __shfl_xor(accA.w, m);
        accB.x += __shfl_xor(accB.x, m); accB.y += __shfl_xor(accB.y, m);
        accB.z += __shfl_xor(accB.z, m); accB.w += __shfl_xor(accB.w, m);
    }
#pragma unroll
    for (int m = 32; m > 0; m >>= 1) ds += __shfl_xor(ds, m);
    const float inv = 1.f / ds;

    if (lane < 16) {
        float4 rA = { eluf(accA.x * inv), eluf(accA.y * inv),
                      eluf(accA.z * inv), eluf(accA.w * inv) };
        float4 rB = { eluf(accB.x * inv), eluf(accB.y * inv),
                      eluf(accB.z * inv), eluf(accB.w * inv) };
        ((float4*)o)[2 * fl]     = rA;
        ((float4*)o)[2 * fl + 1] = rB;
    }
}

// ---------------------------------------------------------------------------
extern "C" void kernel_launch(void* const* d_in, const int* in_sizes, int n_in,
                              void* d_out, int out_size, void* d_ws, size_t ws_size,
                              hipStream_t stream) {
    (void)in_sizes; (void)n_in; (void)out_size; (void)ws_size;
    const float* h   = (const float*)d_in[0];
    const int*   ei  = (const int*)d_in[1];
    const float* Wfc = (const float*)d_in[2];
    const float* Wat = (const float*)d_in[3];
    float* out = (float*)d_out;

    char* ws = (char*)d_ws;
    unsigned short* Wh16 = (unsigned short*)(ws + 0);   // 25,600,000 B
    float*  ssrc2 = (float*)(ws + 25600000);            //    400,000 B  [node][batch]
    float*  sdst2 = (float*)(ws + 26000000);            //    400,000 B
    uint2*  rec0  = (uint2*)(ws + 26400000);            //  6,400,000 B
    uint2*  rec1  = (uint2*)(ws + 32800000);            //  6,400,000 B
    int*    offs  = (int*)  (ws + 39200000);            //    200,448 B
    int*    deg   = (int*)  (ws + 39400448);            //    200,000 B
    int*    cnt2  = (int*)  (ws + 39600448);            //    200,000 B (contiguous w/ deg)
    int*    bsum  = (int*)  (ws + 39800448);            //        256 B
    int*    bscan = (int*)  (ws + 39800704);            //        256 B
    unsigned short* Wsw = (unsigned short*)(ws + 39801088); // 32,768 B pre-swizzled W

    hipMemsetAsync(deg, 0, 400000, stream);   // zero deg + cnt2

    wprep_kernel<<<1, 256, 0, stream>>>(Wfc, Wsw);
    gemm_kernel<<<(NROWS + 63) / 64, 256, 0, stream>>>(h, Wsw, Wat, Wh16, ssrc2, sdst2);
    degree_kernel<<<EE / 256, 256, 0, stream>>>(ei, deg);
    scan1_kernel<<<NB, 1024, 0, stream>>>(deg, offs, bsum);
    scan2_kernel<<<1, 64, 0, stream>>>(bsum, bscan, offs);
    scan3_kernel<<<NB, 1024, 0, stream>>>(offs, bscan);
    scatter_kernel<<<EE / 256, 256, 0, stream>>>(ei, offs, cnt2, ssrc2, sdst2, rec0, rec1);
    aggregate_kernel<<<25000, 256, 0, stream>>>((const unsigned int*)Wh16, offs, rec0, rec1, out);
}

// Round 20
// 173.962 us; speedup vs baseline: 1.1800x; 1.0253x over previous
//
#include <hip/hip_runtime.h>
#include <math.h>

#define NN 50000
#define EE 800000
#define DDIM 128
#define NROWS 100000   // B*N
#define NB 49          // ceil(NN/1024) scan blocks
#define NDEGB 3125     // EE/256 degree blocks

typedef __attribute__((ext_vector_type(8))) short bf16x8;
typedef __attribute__((ext_vector_type(4))) float f32x4;

__device__ __forceinline__ float lrelu(float x) { return x > 0.f ? x : 0.2f * x; }
// fast ELU via hardware v_exp_f32 (abs err ~1e-7, validated r13)
__device__ __forceinline__ float eluf(float x)  {
    float e = __expf(x);
    return x > 0.f ? x : e - 1.f;
}

__device__ __forceinline__ unsigned short f2bf(float f) {
    unsigned int u = __float_as_uint(f);
    u += 0x7fffu + ((u >> 16) & 1u);          // RNE
    return (unsigned short)(u >> 16);
}
__device__ __forceinline__ float bflo(unsigned int v) { return __uint_as_float(v << 16); }
__device__ __forceinline__ float bfhi(unsigned int v) { return __uint_as_float(v & 0xffff0000u); }

// ---------------------------------------------------------------------------
// prep: blocks [0,NDEGB) do degree histogram; block NDEGB converts W fp32 ->
// bf16 PRE-SWIZZLED (chunk q of col c at byte c*256 + ((q^(c&15))<<4)) so
// gemm stages it linearly via global_load_lds.
// ---------------------------------------------------------------------------
__global__ __launch_bounds__(256) void prep_kernel(const int* __restrict__ ei,
                                                   int* __restrict__ deg,
                                                   const float* __restrict__ Wfc,
                                                   unsigned short* __restrict__ Wsw) {
    const int tid = threadIdx.x;
    if (blockIdx.x < NDEGB) {
        int e = blockIdx.x * 256 + tid;        // exact: EE == NDEGB*256
        atomicAdd(&deg[ei[EE + e]], 1);
        return;
    }
    // W prep (one block)
    const int col = tid & 127;
    const int kh  = tid >> 7;                  // 0..1
#pragma unroll
    for (int q8 = 0; q8 < 8; ++q8) {
        int k0 = kh * 64 + q8 * 8;
        float4 w0 = *(const float4*)&Wfc[col * DDIM + k0];
        float4 w1 = *(const float4*)&Wfc[col * DDIM + k0 + 4];
        union { uint4 q4; unsigned short u[8]; } pk;
        pk.u[0] = f2bf(w0.x); pk.u[1] = f2bf(w0.y);
        pk.u[2] = f2bf(w0.z); pk.u[3] = f2bf(w0.w);
        pk.u[4] = f2bf(w1.x); pk.u[5] = f2bf(w1.y);
        pk.u[6] = f2bf(w1.z); pk.u[7] = f2bf(w1.w);
        int chunk = (k0 >> 3) ^ (col & 15);
        *(uint4*)((char*)Wsw + col * 256 + chunk * 16) = pk.q4;
    }
}

// ---------------------------------------------------------------------------
// MFMA GEMM: Wh16[row][o] = bf16( sum_k h[row][k] * Wfc[o][k] )
// W staged to LDS via global_load_lds (pre-swizzled source, linear copy).
// Fused scores written row-indexed: ssrc[row], sdst[row] (row = b*NN+n).
// Tail guard: NROWS%16==0 -> wave-level all-valid/all-invalid.
// ---------------------------------------------------------------------------
__global__ __launch_bounds__(256) void gemm_kernel(const float* __restrict__ h,
                                                   const unsigned short* __restrict__ Wsw,
                                                   const float* __restrict__ Wat,
                                                   unsigned short* __restrict__ Wh16,
                                                   float* __restrict__ ssrc,
                                                   float* __restrict__ sdst) {
    __shared__ unsigned int Wlds_u32[8192];    // 32 KB: 128 cols x 256 B
    __shared__ unsigned short stage[64 * 136]; // 17408 B: 64 rows x 272 B
    char* WldsB  = (char*)Wlds_u32;
    char* stageB = (char*)stage;
    const int tid  = threadIdx.x;
    const int lane = tid & 63;
    const int wv   = tid >> 6;

    // ---- stage W -> LDS: 8 x 1KB async copies per wave (linear) ----
    {
        const char* gsrc = (const char*)Wsw + wv * 8192 + lane * 16;
        unsigned int* ldst = &Wlds_u32[wv * 2048];   // byte base wv*8192
#pragma unroll
        for (int c8 = 0; c8 < 8; ++c8) {
            __builtin_amdgcn_global_load_lds((const unsigned int*)(gsrc + c8 * 1024),
                                             ldst + c8 * 256, 16, 0, 0);
        }
    }

    const long mbase  = (long)blockIdx.x * 64 + wv * 16;
    const bool active = (mbase < NROWS);
    const long mload  = active ? mbase : 0;    // clamp OOB reads for tail waves
    const int c  = lane & 15;                  // A row / D col within tile
    const int kg = lane >> 4;                  // k-group 0..3

    // ---- A fragments: global fp32 -> bf16 regs (overlaps W staging) ----
    union Af { bf16x8 v; unsigned short u[8]; };
    Af af[4];
    const float* arow = h + (mload + c) * DDIM + kg * 8;
#pragma unroll
    for (int kk = 0; kk < 4; ++kk) {
        float4 x = *(const float4*)(arow + kk * 32);
        float4 y = *(const float4*)(arow + kk * 32 + 4);
        af[kk].u[0] = f2bf(x.x); af[kk].u[1] = f2bf(x.y);
        af[kk].u[2] = f2bf(x.z); af[kk].u[3] = f2bf(x.w);
        af[kk].u[4] = f2bf(y.x); af[kk].u[5] = f2bf(y.y);
        af[kk].u[6] = f2bf(y.z); af[kk].u[7] = f2bf(y.w);
    }
    __syncthreads();                           // drains global_load_lds
    if (!active) return;                       // tail waves: no compute/stores

    // ---- MFMA main: 8 col-tiles x 4 k-steps ----
    f32x4 acc[8];
#pragma unroll
    for (int t = 0; t < 8; ++t) acc[t] = (f32x4){0.f, 0.f, 0.f, 0.f};
#pragma unroll
    for (int t = 0; t < 8; ++t) {
        int colbase = (t * 16 + c) * 256;
        int sw = c << 4;
#pragma unroll
        for (int kk = 0; kk < 4; ++kk) {
            int ba = (colbase + kk * 64 + kg * 16) ^ sw;
            bf16x8 b = *(const bf16x8*)(WldsB + ba);
            acc[t] = __builtin_amdgcn_mfma_f32_16x16x32_bf16(af[kk].v, b, acc[t], 0, 0, 0);
        }
    }

    // ---- acc -> LDS stage (D: col = t*16+c, local row = wv*16 + kg*4 + r) ----
#pragma unroll
    for (int t = 0; t < 8; ++t) {
#pragma unroll
        for (int r = 0; r < 4; ++r) {
            int lrow = wv * 16 + kg * 4 + r;
            *(unsigned short*)(stageB + lrow * 272 + (t * 16 + c) * 2) = f2bf(acc[t][r]);
        }
    }
    // wave-local readout: wave's 16 rows = contiguous 4KB in global
    {
        const long gbase = mbase * 256;        // byte offset into Wh16
        const int  lbase = wv * 16 * 272;
#pragma unroll
        for (int q = 0; q < 4; ++q) {
            int f = q * 1024 + lane * 16;      // flat byte idx in wave's 4KB
            uint4 v = *(const uint4*)(stageB + lbase + (f >> 8) * 272 + (f & 255));
            *(uint4*)((char*)Wh16 + gbase + f) = v;
        }
    }

    // ---- fused scores (row-indexed) ----
    float asv[8], adv[8];
#pragma unroll
    for (int t = 0; t < 8; ++t) {
        asv[t] = Wat[t * 16 + c];
        adv[t] = Wat[DDIM + t * 16 + c];
    }
#pragma unroll
    for (int r = 0; r < 4; ++r) {
        float ps = 0.f, pd = 0.f;
#pragma unroll
        for (int t = 0; t < 8; ++t) {
            ps += acc[t][r] * asv[t];
            pd += acc[t][r] * adv[t];
        }
#pragma unroll
        for (int o = 1; o <= 8; o <<= 1) {
            ps += __shfl_xor(ps, o);
            pd += __shfl_xor(pd, o);
        }
        if (c == 0) {
            long row = mbase + kg * 4 + r;
            ssrc[row] = ps;
            sdst[row] = pd;
        }
    }
}

// ---------------------------------------------------------------------------
// scan1: per-block exclusive scan (block-local offs) + block sums
// ---------------------------------------------------------------------------
__global__ __launch_bounds__(1024) void scan1_kernel(const int* __restrict__ deg,
                                                     int* __restrict__ offs,
                                                     int* __restrict__ bsum) {
    __shared__ int wsum[16];
    const int tid = threadIdx.x, lane = tid & 63, wid = tid >> 6;
    const int i = blockIdx.x * 1024 + tid;
    int v = (i < NN) ? deg[i] : 0;
    int x = v;
#pragma unroll
    for (int o = 1; o < 64; o <<= 1) {
        int t = __shfl_up(x, o);
        if (lane >= o) x += t;
    }
    if (lane == 63) wsum[wid] = x;
    __syncthreads();
    if (wid == 0) {
        int s = (lane < 16) ? wsum[lane] : 0;
#pragma unroll
        for (int o = 1; o < 16; o <<= 1) {
            int t = __shfl_up(s, o);
            if (lane >= o) s += t;
        }
        if (lane < 16) wsum[lane] = s;
    }
    __syncthreads();
    int waveoff = (wid > 0) ? wsum[wid - 1] : 0;
    if (i < NN) offs[i] = x - v + waveoff;          // block-local exclusive
    if (tid == 0) bsum[blockIdx.x] = wsum[15];      // block total
}

// scan2: single wave scans NB block sums -> exclusive bscan.
// offs[NN] is written in LOCAL representation (= bsum[NB-1]) so that
// offs[NN] + bscan[NB-1] == EE, matching offs[d]+bscan[d>>10] for d<NN.
__global__ __launch_bounds__(64) void scan2_kernel(const int* __restrict__ bsum,
                                                   int* __restrict__ bscan,
                                                   int* __restrict__ offs) {
    const int lane = threadIdx.x;
    int v = (lane < NB) ? bsum[lane] : 0;
    int x = v;
#pragma unroll
    for (int o = 1; o < 64; o <<= 1) {
        int t = __shfl_up(x, o);
        if (lane >= o) x += t;
    }
    if (lane < NB) bscan[lane] = x - v;
    if (lane == NB - 1) offs[NN] = v;               // local repr of total
}

// scatter: minimal — slot via atomic + 4B src write. No scores, no exp.
__global__ __launch_bounds__(256) void scatter_kernel(const int* __restrict__ ei,
                                                      const int* __restrict__ offs,
                                                      const int* __restrict__ bscan,
                                                      int* __restrict__ cnt2,
                                                      int* __restrict__ slist) {
    int e = blockIdx.x * 256 + threadIdx.x;         // exact grid: EE/256 blocks
    int dst = ei[EE + e];
    int src = ei[e];
    int p = offs[dst] + bscan[dst >> 10] + atomicAdd(&cnt2[dst], 1);
    slist[p] = src;
}

// ---------------------------------------------------------------------------
// aggregate (r16 structure + weight recompute): one wave per (dst, batch);
// b = bid&1 (XCD batch steering). 16 lanes/edge x uint4 = full 256B row;
// 4 edges per load instruction. w recomputed from L2-resident score tables.
// ---------------------------------------------------------------------------
__global__ __launch_bounds__(256) void aggregate_kernel(const unsigned int* __restrict__ Wh16u,
                                                        const int* __restrict__ offs,
                                                        const int* __restrict__ bscan,
                                                        const int* __restrict__ slist,
                                                        const float* __restrict__ ssrc,
                                                        const float* __restrict__ sdst,
                                                        float* __restrict__ out) {
    const int lane = threadIdx.x & 63;
    const int wid  = threadIdx.x >> 6;
    const int bid  = blockIdx.x;
    const int b    = bid & 1;
    const int d    = (bid >> 1) * 4 + wid;

    const int grp = lane >> 4;     // 0..3: which edge of the quad
    const int fl  = lane & 15;     // feature slice (8 feats = 16B)

    float* o = out + ((long)b * NN + d) * DDIM;

    const int base   = offs[d] + bscan[d >> 10];
    const int end    = offs[d + 1] + bscan[(d + 1) >> 10];
    const int degree = end - base;
    if (degree == 0) {
        if (lane < 16) {
            float4 z = {0.f, 0.f, 0.f, 0.f};
            ((float4*)o)[2 * fl]     = z;
            ((float4*)o)[2 * fl + 1] = z;
        }
        return;
    }

    const long boff = (long)b * NN;
    const float sdv = sdst[boff + d];
    const float* ssb = ssrc + boff;
    const unsigned int* WB = Wh16u + boff * 64;

    f32x4 accA = {0,0,0,0}, accB = {0,0,0,0};
    float ds = 0.f;

    for (int ch = 0; ch < degree; ch += 64) {
        int i = ch + lane;
        int s = 0; float w = 0.f;
        if (i < degree) {
            s = slist[base + i];
            w = __expf(lrelu(ssb[s] + sdv));
            ds += w;
        }
        int cnt   = min(64, degree - ch);
        int quads = (cnt + 3) >> 2;
        for (int j = 0; j < quads; ++j) {
            int idx = 4 * j + grp;               // tail lanes carry w=0
            int   sj = __shfl(s, idx);
            float wj = __shfl(w, idx);
            uint4 v = ((const uint4*)(WB + (long)sj * 64))[fl];
            accA.x += wj * bflo(v.x); accA.y += wj * bfhi(v.x);
            accA.z += wj * bflo(v.y); accA.w += wj * bfhi(v.y);
            accB.x += wj * bflo(v.z); accB.y += wj * bfhi(v.z);
            accB.z += wj * bflo(v.w); accB.w += wj * bfhi(v.w);
        }
    }

    // merge the 4 edge-groups (same feature slice at lanes l, l^16, l^32, l^48)
#pragma unroll
    for (int m = 32; m >= 16; m >>= 1) {
        accA.x += __shfl_xor(accA.x, m); accA.y += __shfl_xor(accA.y, m);
        accA.z += __shfl_xor(accA.z, m); accA.w += __shfl_xor(accA.w, m);
        accB.x += __shfl_xor(accB.x, m); accB.y += __shfl_xor(accB.y, m);
        accB.z += __shfl_xor(accB.z, m); accB.w += __shfl_xor(accB.w, m);
    }
#pragma unroll
    for (int m = 32; m > 0; m >>= 1) ds += __shfl_xor(ds, m);
    const float inv = 1.f / ds;

    if (lane < 16) {
        float4 rA = { eluf(accA.x * inv), eluf(accA.y * inv),
                      eluf(accA.z * inv), eluf(accA.w * inv) };
        float4 rB = { eluf(accB.x * inv), eluf(accB.y * inv),
                      eluf(accB.z * inv), eluf(accB.w * inv) };
        ((float4*)o)[2 * fl]     = rA;
        ((float4*)o)[2 * fl + 1] = rB;
    }
}

// ---------------------------------------------------------------------------
extern "C" void kernel_launch(void* const* d_in, const int* in_sizes, int n_in,
                              void* d_out, int out_size, void* d_ws, size_t ws_size,
                              hipStream_t stream) {
    (void)in_sizes; (void)n_in; (void)out_size; (void)ws_size;
    const float* h   = (const float*)d_in[0];
    const int*   ei  = (const int*)d_in[1];
    const float* Wfc = (const float*)d_in[2];
    const float* Wat = (const float*)d_in[3];
    float* out = (float*)d_out;

    char* ws = (char*)d_ws;
    unsigned short* Wh16 = (unsigned short*)(ws + 0);   // 25,600,000 B
    float*  ssrc  = (float*)(ws + 25600000);            //    400,000 B  [row]
    float*  sdst  = (float*)(ws + 26000000);            //    400,000 B
    int*    slist = (int*)  (ws + 26400000);            //  3,200,000 B
    int*    offs  = (int*)  (ws + 29600000);            //    200,448 B
    int*    deg   = (int*)  (ws + 29800448);            //    200,000 B
    int*    cnt2  = (int*)  (ws + 30000448);            //    200,000 B (contiguous w/ deg)
    int*    bsum  = (int*)  (ws + 30200448);            //        256 B
    int*    bscan = (int*)  (ws + 30200704);            //        256 B
    unsigned short* Wsw = (unsigned short*)(ws + 30200960); // 32,768 B pre-swizzled W

    hipMemsetAsync(deg, 0, 400000, stream);   // zero deg + cnt2

    prep_kernel<<<NDEGB + 1, 256, 0, stream>>>(ei, deg, Wfc, Wsw);
    gemm_kernel<<<(NROWS + 63) / 64, 256, 0, stream>>>(h, Wsw, Wat, Wh16, ssrc, sdst);
    scan1_kernel<<<NB, 1024, 0, stream>>>(deg, offs, bsum);
    scan2_kernel<<<1, 64, 0, stream>>>(bsum, bscan, offs);
    scatter_kernel<<<NDEGB, 256, 0, stream>>>(ei, offs, bscan, cnt2, slist);
    aggregate_kernel<<<25000, 256, 0, stream>>>((const unsigned int*)Wh16, offs, bscan,
                                                slist, ssrc, sdst, out);
}